// Round 2
// 241.460 us; speedup vs baseline: 1.0040x; 1.0040x over previous
//
#include <hip/hip_runtime.h>
#include <cmath>
#include <utility>

// Sliding-window min over time, window W=64, per column (Van Herk / Gil-Werman).
// out[t][d] = min(signal[max(0,t-63)..t][d]).
//
// R3 theory: VGPR_Count=52 proves A[64] was NEVER in registers (>=64 values are
// live at each suffix pass) -- it sat in scratch because SROA runs before loop
// unrolling, so runtime-indexed A[i] was unpromotable (guide rule #20). All
// array accesses are now compile-time-constant via template unrolling, so
// first-pass SROA promotes A[] and X[] to VGPRs. Expected ~100 VGPR -> fits the
// 128-VGPR budget of 4 waves/EU, hence __launch_bounds__(256, 4).
// (R1 run died to a container-infra failure; resubmitting the same theory.)

constexpr int T_DIM = 4096;
constexpr int D_DIM = 8192;
constexpr int W = 64;        // window / block length
constexpr int TSEG = 128;    // time rows per workgroup (2 blocks of 64)
constexpr int NB = TSEG / W;
constexpr int CHUNK = 16;    // load-staging batch (16 loads in flight)
constexpr int THREADS = 256;

template <class F, int... Is>
__device__ __forceinline__ void unroll_seq(F&& f, std::integer_sequence<int, Is...>) {
    (f(std::integral_constant<int, Is>{}), ...);
}
template <int N, class F>
__device__ __forceinline__ void unroll(F&& f) {
    unroll_seq(static_cast<F&&>(f), std::make_integer_sequence<int, N>{});
}

__global__ __launch_bounds__(THREADS, 4)
void TemporalOperator_74182675136668_kernel(const float* __restrict__ in,
                                            float* __restrict__ out) {
    const int col = blockIdx.x * THREADS + threadIdx.x;   // one column per thread
    const int t0 = blockIdx.y * TSEG;                     // segment start row
    const float* pin = in + col;
    float* pout = out + col;

    // A[] dual-purpose: suffix-mins of previous 64-block (read at i+1 on iter i),
    // then overwritten in place with current block's raw values (write at i).
    // Every access below has a compile-time-constant index.
    float A[W];

    if (t0 == 0) {
        unroll<W>([&](auto I) { A[I] = INFINITY; });
    } else {
        // Prime: load the 64 rows preceding this segment, build suffix mins.
        const float* pp = pin + (t0 - W) * D_DIM;
        unroll<W>([&](auto I) { A[I] = pp[I * D_DIM]; });
        unroll<W - 1>([&](auto I) {
            constexpr int i = W - 2 - I;
            A[i] = fminf(A[i], A[i + 1]);
        });
    }

#pragma unroll
    for (int b = 0; b < NB; ++b) {
        const int tb = t0 + b * W;
        const float* pb = pin + tb * D_DIM;
        float* po = pout + tb * D_DIM;
        float L = INFINITY;  // running prefix min of current block
        unroll<W / CHUNK>([&](auto C) {
            // Batch 16 independent loads, THEN consume -> 16 loads in flight.
            float X[CHUNK];
            unroll<CHUNK>([&](auto J) { X[J] = pb[(C * CHUNK + J) * D_DIM]; });
            unroll<CHUNK>([&](auto J) {
                constexpr int i = C * CHUNK + J;
                L = fminf(L, X[J]);
                // window [tb+i-63, tb+i] = prev rows [i+1..63] + cur rows [0..i]
                float o;
                if constexpr (i + 1 < W) o = fminf(L, A[i + 1]);
                else                     o = L;
                __builtin_nontemporal_store(o, &po[i * D_DIM]);
                A[i] = X[J];  // slot i is dead (consumed on iter i-1)
            });
        });
        // Turn staged raw values into suffix mins for the next block.
        unroll<W - 1>([&](auto I) {
            constexpr int i = W - 2 - I;
            A[i] = fminf(A[i], A[i + 1]);
        });
    }
}

extern "C" void kernel_launch(void* const* d_in, const int* in_sizes, int n_in,
                              void* d_out, int out_size, void* d_ws, size_t ws_size,
                              hipStream_t stream) {
    const float* in = (const float*)d_in[0];
    float* out = (float*)d_out;
    dim3 grid(D_DIM / THREADS, T_DIM / TSEG);  // 32 x 32 = 1024 blocks
    TemporalOperator_74182675136668_kernel<<<grid, THREADS, 0, stream>>>(in, out);
}

// Round 3
// 237.224 us; speedup vs baseline: 1.0219x; 1.0179x over previous
//
#include <hip/hip_runtime.h>
#include <cmath>
#include <utility>

// Sliding-window min over time, window W=64, per column (Van Herk / Gil-Werman).
// out[t][d] = min(signal[max(0,t-63)..t][d]).
//
// R3: two register-resident variants (runtime-indexed and constant-indexed)
// both sat at 89us/dispatch with VGPR_Count=52 -- the allocator refuses to
// keep the 64-deep suffix state in VGPRs (remat/spill), robust to source
// indexing. This version moves the window state to LDS: S[64][256], thread
// tid owns column tid. Row index is wave-uniform -> lanes hit banks tid%32,
// 2 lanes/bank = conflict-free (m136). No barriers needed (columns are
// thread-private). Load batches are issued BEFORE the previous batch's
// nontemporal stores so vmcnt waits never drain store acks (m135: waitcnt
// retires oldest-first). TSEG=256 halves priming overhead; 512 WGs = 2/CU
// (LDS-capped: 64 KiB/WG).

constexpr int T_DIM = 4096;
constexpr int D_DIM = 8192;
constexpr int W = 64;        // window / block length
constexpr int TSEG = 256;    // time rows per workgroup (4 blocks of 64)
constexpr int NB = TSEG / W;
constexpr int CHUNK = 16;    // load-staging batch (16 loads in flight)
constexpr int NCH = W / CHUNK;
constexpr int THREADS = 256;

template <class F, int... Is>
__device__ __forceinline__ void unroll_seq(F&& f, std::integer_sequence<int, Is...>) {
    (f(std::integral_constant<int, Is>{}), ...);
}
template <int N, class F>
__device__ __forceinline__ void unroll(F&& f) {
    unroll_seq(static_cast<F&&>(f), std::make_integer_sequence<int, N>{});
}

__global__ __launch_bounds__(THREADS, 2)
void TemporalOperator_74182675136668_kernel(const float* __restrict__ in,
                                            float* __restrict__ out) {
    // Window state in LDS: S[row][column]. 64*256*4 = 64 KiB.
    __shared__ float S[W][THREADS];

    const int tid = threadIdx.x;
    const int col = blockIdx.x * THREADS + tid;   // one column per thread
    const int t0 = blockIdx.y * TSEG;             // segment start row
    const float* pin = in + col;
    float* pout = out + col;

    float X[CHUNK], Y[CHUNK];   // load-staging ping-pong (registers)

    if (t0 == 0) {
#pragma unroll
        for (int i = 0; i < W; ++i) S[i][tid] = INFINITY;
    } else {
        // Prime: stage the 64 rows preceding this segment into S, then build
        // suffix mins in place (serial fmin chain in a register, reads are
        // independent ds_reads the scheduler can batch).
        const float* pp = pin + (t0 - W) * D_DIM;
        unroll<CHUNK>([&](auto J) { X[J] = pp[J * D_DIM]; });
#pragma unroll
        for (int c = 0; c < NCH; ++c) {
            if (c + 1 < NCH)
                unroll<CHUNK>([&](auto J) { Y[J] = pp[((c + 1) * CHUNK + J) * D_DIM]; });
            unroll<CHUNK>([&](auto J) { S[c * CHUNK + J][tid] = X[J]; });
            if (c + 1 < NCH)
                unroll<CHUNK>([&](auto J) { X[J] = Y[J]; });
        }
        float s = S[W - 1][tid];
#pragma unroll
        for (int i = W - 2; i >= 0; --i) {
            float x = S[i][tid];
            s = fminf(x, s);
            S[i][tid] = s;
        }
    }

    // Main: S holds suffix-mins of the previous 64-block; consume at i+1 while
    // overwriting slot i with the current block's raw value (slot i is dead).
    unroll<CHUNK>([&](auto J) { X[J] = pin[(t0 + J) * D_DIM]; });

    for (int b = 0; b < NB; ++b) {
        const int tb = t0 + b * W;
        float L = INFINITY;  // running prefix min of current block
#pragma unroll
        for (int c = 0; c < NCH; ++c) {
            // Prefetch the NEXT 16 rows (crosses into the next block at c==3)
            // BEFORE this batch's stores, so load waits never drain store acks.
            const bool pf = (b * W + (c + 1) * CHUNK < TSEG);
            if (pf)
                unroll<CHUNK>([&](auto J) {
                    Y[J] = pin[(tb + (c + 1) * CHUNK + J) * D_DIM];
                });
            unroll<CHUNK>([&](auto J) {
                constexpr int j = J;
                const int i = c * CHUNK + j;
                L = fminf(L, X[j]);
                // window [tb+i-63, tb+i] = prev rows [i+1..63] + cur rows [0..i]
                const float o = (i + 1 < W) ? fminf(L, S[i + 1][tid]) : L;
                __builtin_nontemporal_store(o, &pout[(tb + i) * D_DIM]);
                S[i][tid] = X[j];  // slot i consumed on iter i-1
            });
            if (pf)
                unroll<CHUNK>([&](auto J) { X[J] = Y[J]; });
        }
        // Turn staged raw values into suffix mins for the next block.
        // (Next block's first loads are already in flight -> latency hidden.)
        if (b + 1 < NB) {
            float s = S[W - 1][tid];
#pragma unroll
            for (int i = W - 2; i >= 0; --i) {
                float x = S[i][tid];
                s = fminf(x, s);
                S[i][tid] = s;
            }
        }
    }
}

extern "C" void kernel_launch(void* const* d_in, const int* in_sizes, int n_in,
                              void* d_out, int out_size, void* d_ws, size_t ws_size,
                              hipStream_t stream) {
    const float* in = (const float*)d_in[0];
    float* out = (float*)d_out;
    dim3 grid(D_DIM / THREADS, T_DIM / TSEG);  // 32 x 16 = 512 blocks
    TemporalOperator_74182675136668_kernel<<<grid, THREADS, 0, stream>>>(in, out);
}

// Round 4
// 230.344 us; speedup vs baseline: 1.0524x; 1.0299x over previous
//
#include <hip/hip_runtime.h>
#include <cmath>
#include <utility>

// Sliding-window min over time, window W=64, per column (Van Herk / Gil-Werman).
// out[t][d] = min(signal[max(0,t-63)..t][d]).
//
// R4: R0/R2/R3 (scratch-state, reg-state, LDS-state) all hit the same ~88us
// floor at 2.5 TB/s HBM -- state location is irrelevant. Common factor: 4B/lane
// accesses (256B/wave bursts, 4 cache lines of MLP per vmem inst), measured
// ~330 cy per wave-row = latency-serialized. This version vectorizes the whole
// pipeline to float2: 8B/lane, 512B/wave bursts, half the vmem instructions,
// 2x bytes in flight per load slot. Window state in LDS S[64][128] float2 =
// exactly 64 KiB (safe static limit) -> THREADS=128, 2 WG/CU, 4 waves/CU.
// Prefetch is a compile-time-parity double buffer (no reg copies, all indices
// constant -> SROA keeps buffers in VGPRs).

constexpr int T_DIM = 4096;
constexpr int D_DIM = 8192;
constexpr int W = 64;            // window / block length
constexpr int TSEG = 256;        // time rows per workgroup (4 blocks of 64)
constexpr int NB = TSEG / W;     // 4
constexpr int CHUNK = 16;        // load-staging batch (16 loads in flight)
constexpr int NCH = W / CHUNK;   // 4
constexpr int THREADS = 128;
constexpr int PITCH2 = D_DIM / 2;  // row pitch in float2 units

typedef float v2f __attribute__((ext_vector_type(2)));

template <class F, int... Is>
__device__ __forceinline__ void unroll_seq(F&& f, std::integer_sequence<int, Is...>) {
    (f(std::integral_constant<int, Is>{}), ...);
}
template <int N, class F>
__device__ __forceinline__ void unroll(F&& f) {
    unroll_seq(static_cast<F&&>(f), std::make_integer_sequence<int, N>{});
}

__device__ __forceinline__ v2f vmin2(v2f a, v2f b) {
    v2f r;
    r[0] = fminf(a[0], b[0]);
    r[1] = fminf(a[1], b[1]);
    return r;
}

__global__ __launch_bounds__(THREADS, 1)
void TemporalOperator_74182675136668_kernel(const float* __restrict__ in,
                                            float* __restrict__ out) {
    // Window state: S[row][thread], thread owns 2 adjacent columns. 64 KiB.
    // ds_*_b64: lanes 0..15 cover all 32 banks -> balanced, conflict-free.
    __shared__ v2f S[W][THREADS];

    const int tid = threadIdx.x;
    const int col2 = blockIdx.x * THREADS + tid;   // float2-column index
    const int t0 = blockIdx.y * TSEG;              // segment start row
    const v2f* pin = (const v2f*)in + col2;
    v2f* pout = (v2f*)out + col2;

    if (t0 == 0) {
#pragma unroll
        for (int i = 0; i < W; ++i) {
            v2f z; z[0] = INFINITY; z[1] = INFINITY;
            S[i][tid] = z;
        }
    } else {
        // Prime: stage the 64 rows preceding this segment, build suffix mins.
        const v2f* pp = pin + (t0 - W) * PITCH2;
#pragma unroll
        for (int c = 0; c < NCH; ++c) {
            v2f tmp[CHUNK];
            unroll<CHUNK>([&](auto J) { tmp[J] = pp[(c * CHUNK + J) * PITCH2]; });
            unroll<CHUNK>([&](auto J) { S[c * CHUNK + J][tid] = tmp[J]; });
        }
        v2f s = S[W - 1][tid];
#pragma unroll
        for (int i = W - 2; i >= 0; --i) {
            v2f x = S[i][tid];
            s = vmin2(s, x);
            S[i][tid] = s;
        }
    }

    // Main loop. S holds suffix-mins of the previous 64-block; consume S[i+1]
    // while overwriting slot i with the current block's raw value (slot i is
    // dead -- consumed on iteration i-1).
    v2f buf[2][CHUNK];  // compile-time-parity ping-pong, lives in VGPRs
    unroll<CHUNK>([&](auto J) { buf[0][J] = pin[(t0 + J) * PITCH2]; });

    for (int b = 0; b < NB; ++b) {
        const int tb = t0 + b * W;
        v2f L; L[0] = INFINITY; L[1] = INFINITY;  // running prefix min
        unroll<NCH>([&](auto C) {
            constexpr int p = C & 1;
            // Prefetch the NEXT 16 rows (crosses into the next block at C==3:
            // parity (p^1)==0 matches next block's C==0 read buffer) BEFORE
            // this batch's stores, so load waits never drain store acks.
            const bool pf = (b * W + (C + 1) * CHUNK < TSEG);
            if (pf)
                unroll<CHUNK>([&](auto J) {
                    buf[p ^ 1][J] = pin[(tb + (C + 1) * CHUNK + J) * PITCH2];
                });
            unroll<CHUNK>([&](auto J) {
                constexpr int i = C * CHUNK + J;
                L = vmin2(L, buf[p][J]);
                // window [tb+i-63, tb+i] = prev rows [i+1..63] + cur rows [0..i]
                v2f o;
                if constexpr (i + 1 < W) o = vmin2(L, S[i + 1][tid]);
                else                     o = L;
                __builtin_nontemporal_store(o, &pout[(tb + i) * PITCH2]);
                S[i][tid] = buf[p][J];  // slot i consumed on iter i-1
            });
        });
        // Turn staged raw values into suffix mins for the next block.
        // (Next block's first 16 loads are already in flight.)
        if (b + 1 < NB) {
            v2f s = S[W - 1][tid];
#pragma unroll
            for (int i = W - 2; i >= 0; --i) {
                v2f x = S[i][tid];
                s = vmin2(s, x);
                S[i][tid] = s;
            }
        }
    }
}

extern "C" void kernel_launch(void* const* d_in, const int* in_sizes, int n_in,
                              void* d_out, int out_size, void* d_ws, size_t ws_size,
                              hipStream_t stream) {
    const float* in = (const float*)d_in[0];
    float* out = (float*)d_out;
    dim3 grid(PITCH2 / THREADS, T_DIM / TSEG);  // 32 x 16 = 512 blocks
    TemporalOperator_74182675136668_kernel<<<grid, THREADS, 0, stream>>>(in, out);
}